// Round 5
// baseline (560.011 us; speedup 1.0000x reference)
//
#include <hip/hip_runtime.h>
#include <math.h>
#include <stdint.h>

#define BB 1024
#define SS 200
#define HH 128
#define NI 100000

typedef __attribute__((ext_vector_type(8))) short short8;  // 8 bf16 (4 VGPRs)
typedef __attribute__((ext_vector_type(4))) float f32x4;   // MFMA C/D

// tanh(x) = sign(x) * (1 - e^{-2|x|}) / (1 + e^{-2|x|})
__device__ __forceinline__ float fast_tanh(float x) {
    float ax = fabsf(x);
    float t = __expf(-2.0f * ax);
    float r = (1.0f - t) / (1.0f + t);
    return copysignf(r, x);
}

// Split 8 consecutive fp32 into bf16 hi + bf16 lo (truncation split; residual
// captured exactly, dropped lo*lo term ~2^-16 relative).
__device__ __forceinline__ void split8(const float* __restrict__ p,
                                       short8& hi, short8& lo) {
    const float4* p4 = reinterpret_cast<const float4*>(p);
    float4 x0 = p4[0], x1 = p4[1];
    float v[8] = {x0.x, x0.y, x0.z, x0.w, x1.x, x1.y, x1.z, x1.w};
    #pragma unroll
    for (int j = 0; j < 8; ++j) {
        unsigned u = __float_as_uint(v[j]);
        unsigned short h = (unsigned short)(u >> 16);
        hi[j] = (short)h;
        float r = v[j] - __uint_as_float(((unsigned)h) << 16);
        lo[j] = (short)(__float_as_uint(r) >> 16);
    }
}

// ---------------------------------------------------------------------------
// Prep kernel (runs once per iteration, ~5us):
//   blocks 0..511 : lm[b][k] = sum_h last[b][h] * Wr[k][h]   (bit-identical
//                   FMA order to the original per-block computation)
//   blocks 512..519: split Ur into bf16 hi/lo fragment tables, laid out so a
//                   wave's fragment load for fixed (c,n) is 64 lanes x 16B
//                   fully contiguous: rec = c*512 + n*64 + quad*16 + col
// ---------------------------------------------------------------------------
__global__ __launch_bounds__(256)
void rrd_prep_kernel(const float* __restrict__ lastm,   // [B,H]
                     const float* __restrict__ Wr,      // [H,H]
                     const float* __restrict__ Ur,      // [H,H]
                     float* __restrict__ lm_ws,         // [B,H]
                     short* __restrict__ ur_hi,         // [2048] short8
                     short* __restrict__ ur_lo) {       // [2048] short8
    const int blk = blockIdx.x;
    const int tid = threadIdx.x;
    if (blk < 512) {
        const int gid = blk * 256 + tid;       // 131072 = B*H outputs
        const int b = gid >> 7;
        const int k = gid & 127;
        const float4* wrow = reinterpret_cast<const float4*>(Wr + (size_t)k * HH);
        const float4* lrow = reinterpret_cast<const float4*>(lastm + (size_t)b * HH);
        float4 acc = make_float4(0.f, 0.f, 0.f, 0.f);
        #pragma unroll
        for (int i = 0; i < HH / 4; ++i) {
            float4 wv = wrow[i];
            float4 lv = lrow[i];
            acc.x = fmaf(lv.x, wv.x, acc.x);
            acc.y = fmaf(lv.y, wv.y, acc.y);
            acc.z = fmaf(lv.z, wv.z, acc.z);
            acc.w = fmaf(lv.w, wv.w, acc.w);
        }
        lm_ws[gid] = (acc.x + acc.y) + (acc.z + acc.w);
    } else {
        const int r = (blk - 512) * 256 + tid;  // 0..2047 fragment records
        const int c    = r >> 9;
        const int n    = (r >> 6) & 7;
        const int quad = (r >> 4) & 3;
        const int col  = r & 15;
        const int row = n * 16 + col;           // Ur row (output k index)
        const int k0  = c * 32 + quad * 8;      // Ur col (inner h index)
        short8 hi, lo;
        split8(Ur + (size_t)row * HH + k0, hi, lo);
        reinterpret_cast<short8*>(ur_hi)[r] = hi;
        reinterpret_cast<short8*>(ur_lo)[r] = lo;
    }
}

// ---------------------------------------------------------------------------
// K_scores: 4096 blocks (4 per batch row), each wave computes ONE 16-row
// m-tile x 128 cols. 4x the blocks / (1/4) the per-wave chain length of the
// fused kernel -> device-level pipelining across staggered blocks. Each block
// also zero-fills its 1/4096 slice of out (fill stays overlapped with other
// blocks' compute, per round-2's lesson). Math is verbatim from the verified
// kernel: identical MFMA order, fmaf order, shuffle order.
// ---------------------------------------------------------------------------
__global__ __launch_bounds__(256, 3)
void rrd_scores_kernel(const float* __restrict__ allm,      // [B,S,H]
                       const short* __restrict__ ur_hi,     // prefab frags
                       const short* __restrict__ ur_lo,
                       const float* __restrict__ lm_ws,     // [B,H]
                       const float* __restrict__ Vr,        // [1,H]
                       float* __restrict__ scores_ws,       // [B,S]
                       float* __restrict__ out) {           // [B,N]
    const int blk = blockIdx.x;       // 4096
    const int b    = blk >> 2;
    const int tile = blk & 3;         // 64-row tile within the batch row
    const int tid = threadIdx.x;
    const int lane = tid & 63;
    const int w = tid >> 6;           // wave id: m-tile rows tile*64+w*16 ..
    const int col = lane & 15;        // C col / A m lane index
    const int quad = lane >> 4;       // k-quad (8 k each)

    __shared__ float s_lm[HH];
    __shared__ float s_vr[HH];

    if (tid < HH) s_lm[tid] = lm_ws[(size_t)b * HH + tid];
    else          s_vr[tid - HH] = Vr[tid - HH];
    __syncthreads();

    const short8* uh = reinterpret_cast<const short8*>(ur_hi);
    const short8* ul = reinterpret_cast<const short8*>(ur_lo);

    int row = tile * 64 + w * 16 + col;
    if (row > SS - 1) row = SS - 1;   // clamp: pad rows read real data

    f32x4 C[8] = {};                  // 32 VGPRs accum
    // default unrolling: let the compiler pipeline loads of chunk c+1 under
    // the MFMAs of chunk c (register headroom exists at (256,3): ~120/170)
    #pragma unroll
    for (int c = 0; c < 4; ++c) {     // K chunks of 32
        short8 Bh[8], Bl[8];
        const int rbase = c * 512 + quad * 16 + col;
        #pragma unroll
        for (int n = 0; n < 8; ++n) { // prefab B frag, 1KB/wave contiguous
            Bh[n] = uh[rbase + n * 64];
            Bl[n] = ul[rbase + n * 64];
        }
        const float* ap = allm + ((size_t)b * SS + row) * HH + c * 32 + quad * 8;
        short8 Ah, Al;
        split8(ap, Ah, Al);
        #pragma unroll
        for (int n = 0; n < 8; ++n) {
            C[n] = __builtin_amdgcn_mfma_f32_16x16x32_bf16(Ah, Bh[n], C[n], 0, 0, 0);
            C[n] = __builtin_amdgcn_mfma_f32_16x16x32_bf16(Ah, Bl[n], C[n], 0, 0, 0);
            C[n] = __builtin_amdgcn_mfma_f32_16x16x32_bf16(Al, Bh[n], C[n], 0, 0, 0);
        }
    }

    // ---- epilogue in C layout: col=lane&15, row=quad*4+reg (verbatim) ----
    float a0 = 0.f, a1 = 0.f, a2 = 0.f, a3 = 0.f;
    #pragma unroll
    for (int n = 0; n < 8; ++n) {
        float lmc = s_lm[n * 16 + col];
        float vrc = s_vr[n * 16 + col];
        a0 = fmaf(vrc, fast_tanh(C[n][0] + lmc), a0);
        a1 = fmaf(vrc, fast_tanh(C[n][1] + lmc), a1);
        a2 = fmaf(vrc, fast_tanh(C[n][2] + lmc), a2);
        a3 = fmaf(vrc, fast_tanh(C[n][3] + lmc), a3);
    }
    #pragma unroll
    for (int off = 1; off < 16; off <<= 1) {
        a0 += __shfl_xor(a0, off, 64);
        a1 += __shfl_xor(a1, off, 64);
        a2 += __shfl_xor(a2, off, 64);
        a3 += __shfl_xor(a3, off, 64);
    }
    if (col == 0) {
        const int rb = tile * 64 + w * 16 + quad * 4;
        float* srow = scores_ws + (size_t)b * SS;
        if (rb + 0 < SS) srow[rb + 0] = a0;
        if (rb + 1 < SS) srow[rb + 1] = a1;
        if (rb + 2 < SS) srow[rb + 2] = a2;
        if (rb + 3 < SS) srow[rb + 3] = a3;
    }

    // ---- zero-fill this block's 1/4096 slice of out (25000 floats).
    //      No barrier needed: kernel-end drains stores; the scatter kernel
    //      is stream-ordered after us. Blocks stagger -> fill overlaps other
    //      blocks' MFMA/load phases. ----
    {
        const float4 z4 = make_float4(0.f, 0.f, 0.f, 0.f);
        float4* o4 = reinterpret_cast<float4*>(out) + (size_t)blk * 6250;
        for (int i = tid; i < 6250; i += 256) o4[i] = z4;
    }
}

// ---------------------------------------------------------------------------
// K_out: softmax over S + scatter-add. Verbatim softmax flow from the
// verified kernel (bit-identical); scores come from workspace instead of LDS.
// Atomics are ordered after K_scores' zero-fill by the kernel boundary.
// ---------------------------------------------------------------------------
__global__ __launch_bounds__(256)
void rrd_out_kernel(const float* __restrict__ scores_ws,   // [B,S]
                    const int* __restrict__ item_seq,      // [B,S]
                    const unsigned char* __restrict__ mask,// [B,S]
                    const float* __restrict__ Vrb,         // [1]
                    float* __restrict__ out) {             // [B,N]
    const int b = blockIdx.x;
    const int tid = threadIdx.x;
    const int lane = tid & 63;
    const int w = tid >> 6;
    __shared__ float s_red[8];

    const int s = tid;
    float score = ((s < SS) ? scores_ws[(size_t)b * SS + s] : 0.f) + Vrb[0];
    if (s < SS && mask[b * SS + s]) score = -1e9f;

    float v = (s < SS) ? score : -3.0e38f;
    #pragma unroll
    for (int off = 32; off > 0; off >>= 1)
        v = fmaxf(v, __shfl_down(v, off, 64));
    if (lane == 0) s_red[w] = v;
    __syncthreads();
    float m = fmaxf(fmaxf(s_red[0], s_red[1]), fmaxf(s_red[2], s_red[3]));

    float e = (s < SS) ? __expf(score - m) : 0.f;
    float sv = e;
    #pragma unroll
    for (int off = 32; off > 0; off >>= 1)
        sv += __shfl_down(sv, off, 64);
    if (lane == 0) s_red[4 + w] = sv;
    __syncthreads();
    float tot = (s_red[4] + s_red[5]) + (s_red[6] + s_red[7]);

    if (s < SS) {
        float att = e / tot;
        int idx = item_seq[b * SS + s];
        atomicAdd(out + (size_t)b * NI + idx, att);
    }
}

// ---------------------------------------------------------------------------
// Fallback: original fused kernel (used only if ws_size is too small).
// ---------------------------------------------------------------------------
__global__ __launch_bounds__(256, 2)
void rrd_mfma_kernel(const float* __restrict__ allm,      // [B,S,H]
                     const float* __restrict__ lastm,     // [B,H]
                     const int* __restrict__ item_seq,    // [B,S]
                     const unsigned char* __restrict__ mask, // [B,S]
                     const float* __restrict__ Ur,        // [H,H]
                     const float* __restrict__ Wr,        // [H,H]
                     const float* __restrict__ Vr,        // [1,H]
                     const float* __restrict__ Vrb,       // [1]
                     float* __restrict__ out) {           // [B,N]
    const int b = blockIdx.x;
    const int tid = threadIdx.x;
    const int lane = tid & 63;
    const int w = tid >> 6;
    const int col = lane & 15;
    const int quad = lane >> 4;

    __shared__ float s_last[HH];
    __shared__ float s_lm[HH];
    __shared__ float s_vr[HH];
    __shared__ float s_score[256];
    __shared__ float s_red[8];

    if (tid < HH) s_last[tid] = lastm[b * HH + tid];
    else          s_vr[tid - HH] = Vr[tid - HH];
    __syncthreads();

    if (tid < HH) {
        const float4* wrow = reinterpret_cast<const float4*>(Wr + tid * HH);
        const float4* lrow = reinterpret_cast<const float4*>(s_last);
        float4 acc = make_float4(0.f, 0.f, 0.f, 0.f);
        #pragma unroll
        for (int i = 0; i < HH / 4; ++i) {
            float4 wv = wrow[i];
            float4 lv = lrow[i];
            acc.x = fmaf(lv.x, wv.x, acc.x);
            acc.y = fmaf(lv.y, wv.y, acc.y);
            acc.z = fmaf(lv.z, wv.z, acc.z);
            acc.w = fmaf(lv.w, wv.w, acc.w);
        }
        s_lm[tid] = (acc.x + acc.y) + (acc.z + acc.w);
    }
    __syncthreads();

    const int row0 = w * 64;
    #pragma unroll 1
    for (int p = 0; p < 2; ++p) {
        f32x4 C[2][8] = {};
        #pragma unroll 1
        for (int c = 0; c < 4; ++c) {
            short8 Bh[8], Bl[8];
            #pragma unroll
            for (int n = 0; n < 8; ++n) {
                const float* bp = Ur + (size_t)(n * 16 + col) * HH + c * 32 + quad * 8;
                split8(bp, Bh[n], Bl[n]);
            }
            #pragma unroll
            for (int t = 0; t < 2; ++t) {
                int row = row0 + (p * 2 + t) * 16 + col;
                if (row > SS - 1) row = SS - 1;
                const float* ap = allm + ((size_t)b * SS + row) * HH + c * 32 + quad * 8;
                short8 Ah, Al;
                split8(ap, Ah, Al);
                #pragma unroll
                for (int n = 0; n < 8; ++n) {
                    C[t][n] = __builtin_amdgcn_mfma_f32_16x16x32_bf16(Ah, Bh[n], C[t][n], 0, 0, 0);
                    C[t][n] = __builtin_amdgcn_mfma_f32_16x16x32_bf16(Ah, Bl[n], C[t][n], 0, 0, 0);
                    C[t][n] = __builtin_amdgcn_mfma_f32_16x16x32_bf16(Al, Bh[n], C[t][n], 0, 0, 0);
                }
            }
        }
        #pragma unroll
        for (int t = 0; t < 2; ++t) {
            float a0 = 0.f, a1 = 0.f, a2 = 0.f, a3 = 0.f;
            #pragma unroll
            for (int n = 0; n < 8; ++n) {
                float lmc = s_lm[n * 16 + col];
                float vrc = s_vr[n * 16 + col];
                a0 = fmaf(vrc, fast_tanh(C[t][n][0] + lmc), a0);
                a1 = fmaf(vrc, fast_tanh(C[t][n][1] + lmc), a1);
                a2 = fmaf(vrc, fast_tanh(C[t][n][2] + lmc), a2);
                a3 = fmaf(vrc, fast_tanh(C[t][n][3] + lmc), a3);
            }
            #pragma unroll
            for (int off = 1; off < 16; off <<= 1) {
                a0 += __shfl_xor(a0, off, 64);
                a1 += __shfl_xor(a1, off, 64);
                a2 += __shfl_xor(a2, off, 64);
                a3 += __shfl_xor(a3, off, 64);
            }
            if (col == 0) {
                int rb = row0 + (p * 2 + t) * 16 + quad * 4;
                s_score[rb + 0] = a0;
                s_score[rb + 1] = a1;
                s_score[rb + 2] = a2;
                s_score[rb + 3] = a3;
            }
        }
    }

    {
        float4* orow = reinterpret_cast<float4*>(out + (size_t)b * NI);
        const float4 z4 = make_float4(0.f, 0.f, 0.f, 0.f);
        for (int i = tid; i < NI / 4; i += 256) orow[i] = z4;
    }

    __syncthreads();

    const int s = tid;
    float score = s_score[s] + Vrb[0];
    if (s < SS && mask[b * SS + s]) score = -1e9f;

    float v = (s < SS) ? score : -3.0e38f;
    #pragma unroll
    for (int off = 32; off > 0; off >>= 1)
        v = fmaxf(v, __shfl_down(v, off, 64));
    if (lane == 0) s_red[w] = v;
    __syncthreads();
    float m = fmaxf(fmaxf(s_red[0], s_red[1]), fmaxf(s_red[2], s_red[3]));

    float e = (s < SS) ? __expf(score - m) : 0.f;
    float sv = e;
    #pragma unroll
    for (int off = 32; off > 0; off >>= 1)
        sv += __shfl_down(sv, off, 64);
    if (lane == 0) s_red[4 + w] = sv;
    __syncthreads();
    float tot = (s_red[4] + s_red[5]) + (s_red[6] + s_red[7]);

    if (s < SS) {
        float att = e / tot;
        int idx = item_seq[b * SS + s];
        atomicAdd(out + (size_t)b * NI + idx, att);
    }
}

extern "C" void kernel_launch(void* const* d_in, const int* in_sizes, int n_in,
                              void* d_out, int out_size, void* d_ws, size_t ws_size,
                              hipStream_t stream) {
    const float* allm   = (const float*)d_in[0];
    const float* lastm  = (const float*)d_in[1];
    const int*   iseq   = (const int*)d_in[2];
    const unsigned char* mask = (const unsigned char*)d_in[3];
    const float* Ur     = (const float*)d_in[4];
    const float* Wr     = (const float*)d_in[5];
    const float* Vr     = (const float*)d_in[6];
    const float* Vrb    = (const float*)d_in[7];
    float* out          = (float*)d_out;

    const size_t lm_bytes = (size_t)BB * HH * sizeof(float);    // 512 KB
    const size_t ur_bytes = (size_t)HH * HH * sizeof(short);    // 32 KB each
    const size_t sc_bytes = (size_t)BB * SS * sizeof(float);    // 800 KB
    const size_t need = lm_bytes + 2 * ur_bytes + sc_bytes;     // ~1.38 MB

    if (d_ws != nullptr && ws_size >= need) {
        float* lm_ws     = (float*)d_ws;
        short* ur_hi     = (short*)((char*)d_ws + lm_bytes);
        short* ur_lo     = (short*)((char*)d_ws + lm_bytes + ur_bytes);
        float* scores_ws = (float*)((char*)d_ws + lm_bytes + 2 * ur_bytes);
        rrd_prep_kernel<<<dim3(520), dim3(256), 0, stream>>>(
            lastm, Wr, Ur, lm_ws, ur_hi, ur_lo);
        rrd_scores_kernel<<<dim3(4096), dim3(256), 0, stream>>>(
            allm, ur_hi, ur_lo, lm_ws, Vr, scores_ws, out);
        rrd_out_kernel<<<dim3(BB), dim3(256), 0, stream>>>(
            scores_ws, iseq, mask, Vrb, out);
    } else {
        rrd_mfma_kernel<<<dim3(BB), dim3(256), 0, stream>>>(
            allm, lastm, iseq, mask, Ur, Wr, Vr, Vrb, out);
    }
}

// Round 6
// 530.438 us; speedup vs baseline: 1.0558x; 1.0558x over previous
//
#include <hip/hip_runtime.h>
#include <math.h>
#include <stdint.h>

#define BB 1024
#define SS 200
#define HH 128
#define NI 100000

typedef __attribute__((ext_vector_type(8))) short short8;  // 8 bf16 (4 VGPRs)
typedef __attribute__((ext_vector_type(4))) float f32x4;   // MFMA C/D

// tanh(x) = sign(x) * (1 - e^{-2|x|}) / (1 + e^{-2|x|})
__device__ __forceinline__ float fast_tanh(float x) {
    float ax = fabsf(x);
    float t = __expf(-2.0f * ax);
    float r = (1.0f - t) / (1.0f + t);
    return copysignf(r, x);
}

// Split 8 consecutive fp32 (given as two float4 registers) into bf16 hi + lo.
// Identical arithmetic to the original pointer-based split8.
__device__ __forceinline__ void split8r(float4 x0, float4 x1,
                                        short8& hi, short8& lo) {
    float v[8] = {x0.x, x0.y, x0.z, x0.w, x1.x, x1.y, x1.z, x1.w};
    #pragma unroll
    for (int j = 0; j < 8; ++j) {
        unsigned u = __float_as_uint(v[j]);
        unsigned short h = (unsigned short)(u >> 16);
        hi[j] = (short)h;
        float r = v[j] - __uint_as_float(((unsigned)h) << 16);
        lo[j] = (short)(__float_as_uint(r) >> 16);
    }
}

__device__ __forceinline__ void split8(const float* __restrict__ p,
                                       short8& hi, short8& lo) {
    const float4* p4 = reinterpret_cast<const float4*>(p);
    split8r(p4[0], p4[1], hi, lo);
}

// ---------------------------------------------------------------------------
// Prep kernel (runs once per iteration, ~5us):
//   blocks 0..511 : lm[b][k] = sum_h last[b][h] * Wr[k][h]   (bit-identical
//                   FMA order to the original per-block computation)
//   blocks 512..519: split Ur into bf16 hi/lo fragment tables, laid out so a
//                   wave's fragment load for fixed (c,n) is 64 lanes x 16B
//                   fully contiguous: rec = c*512 + n*64 + quad*16 + col
// ---------------------------------------------------------------------------
__global__ __launch_bounds__(256)
void rrd_prep_kernel(const float* __restrict__ lastm,   // [B,H]
                     const float* __restrict__ Wr,      // [H,H]
                     const float* __restrict__ Ur,      // [H,H]
                     float* __restrict__ lm_ws,         // [B,H]
                     short* __restrict__ ur_hi,         // [2048] short8
                     short* __restrict__ ur_lo) {       // [2048] short8
    const int blk = blockIdx.x;
    const int tid = threadIdx.x;
    if (blk < 512) {
        const int gid = blk * 256 + tid;       // 131072 = B*H outputs
        const int b = gid >> 7;
        const int k = gid & 127;
        const float4* wrow = reinterpret_cast<const float4*>(Wr + (size_t)k * HH);
        const float4* lrow = reinterpret_cast<const float4*>(lastm + (size_t)b * HH);
        float4 acc = make_float4(0.f, 0.f, 0.f, 0.f);
        #pragma unroll
        for (int i = 0; i < HH / 4; ++i) {
            float4 wv = wrow[i];
            float4 lv = lrow[i];
            acc.x = fmaf(lv.x, wv.x, acc.x);
            acc.y = fmaf(lv.y, wv.y, acc.y);
            acc.z = fmaf(lv.z, wv.z, acc.z);
            acc.w = fmaf(lv.w, wv.w, acc.w);
        }
        lm_ws[gid] = (acc.x + acc.y) + (acc.z + acc.w);
    } else {
        const int r = (blk - 512) * 256 + tid;  // 0..2047 fragment records
        const int c    = r >> 9;
        const int n    = (r >> 6) & 7;
        const int quad = (r >> 4) & 3;
        const int col  = r & 15;
        const int row = n * 16 + col;           // Ur row (output k index)
        const int k0  = c * 32 + quad * 8;      // Ur col (inner h index)
        short8 hi, lo;
        split8(Ur + (size_t)row * HH + k0, hi, lo);
        reinterpret_cast<short8*>(ur_hi)[r] = hi;
        reinterpret_cast<short8*>(ur_lo)[r] = lo;
    }
}

// ---------------------------------------------------------------------------
// Main kernel = R1's 524us structure with CHAIN SURGERY ONLY:
//   * p x c loops flattened to one 8-step loop; A-loads for step q+1 issued
//     BEFORE the B-loads/split/MFMA of step q (software pipeline) -> the
//     ~500-900cy A-load latency is exposed only at step 0, hidden under
//     compute (and under the pass-0 epilogue at the pass boundary) elsewhere.
//   * wave 3 exits after pass 0: its pass-1 tiles (rows 224..255) are fully
//     clamped padding. Its SIMD starts the fill slice early.
//   * Everything else verbatim: per-accumulator MFMA order, epilogue math,
//     in-kernel zero-fill placement, softmax, scatter. Bit-exact output.
// ---------------------------------------------------------------------------
__global__ __launch_bounds__(256, 2)
void rrd_mfma_kernel_p(const float* __restrict__ allm,      // [B,S,H]
                       const int* __restrict__ item_seq,    // [B,S]
                       const unsigned char* __restrict__ mask, // [B,S]
                       const short* __restrict__ ur_hi,     // prefab frags
                       const short* __restrict__ ur_lo,
                       const float* __restrict__ lm_ws,     // [B,H]
                       const float* __restrict__ Vr,        // [1,H]
                       const float* __restrict__ Vrb,       // [1]
                       float* __restrict__ out) {           // [B,N]
    const int b = blockIdx.x;
    const int tid = threadIdx.x;
    const int lane = tid & 63;
    const int w = tid >> 6;       // wave id: rows [64w, 64w+64)
    const int col = lane & 15;    // C col / B n / A m lane index
    const int quad = lane >> 4;   // k-quad (8 k each)

    __shared__ float s_lm[HH];
    __shared__ float s_vr[HH];
    __shared__ float s_score[256];
    __shared__ float s_red[8];

    // ---- stage lm + Vr into LDS ----
    if (tid < HH) s_lm[tid] = lm_ws[(size_t)b * HH + tid];
    else          s_vr[tid - HH] = Vr[tid - HH];
    __syncthreads();   // s_lm/s_vr ready for epilogue

    const short8* uh = reinterpret_cast<const short8*>(ur_hi);
    const short8* ul = reinterpret_cast<const short8*>(ur_lo);

    const int row0 = w * 64;
    // tile liveness (wave-uniform): tile (p,t) base row = row0 + (p*2+t)*16
    const bool live1_p0 = (row0 + 16) < SS;   // false only for w=3
    const bool live_p1  = (row0 + 32) < SS;   // false only for w=3
    const bool live1_p1 = (row0 + 48) < SS;
    const int QMAX = live_p1 ? 8 : 4;         // wave 3 skips pass 1 entirely

    // A address for (pass p, tile t, chunk c), row clamped (pads read row 199)
    auto aPtr = [&](int p, int t, int c) -> const float4* {
        int r = row0 + (p * 2 + t) * 16 + col;
        if (r > SS - 1) r = SS - 1;
        return reinterpret_cast<const float4*>(
            allm + ((size_t)b * SS + r) * HH + c * 32 + quad * 8);
    };

    f32x4 C[2][8] = {};   // fp32 accum (per pass; reset at pass boundary)

    // ---- prologue: preload A for step q=0 (p=0,c=0) ----
    float4 a0x, a0y, a1x, a1y;
    { const float4* p0 = aPtr(0, 0, 0); a0x = p0[0]; a0y = p0[1];
      const float4* p1 = aPtr(0, 1, 0); a1x = p1[0]; a1y = p1[1]; }

    #pragma unroll 1
    for (int q = 0; q < QMAX; ++q) {
        const int p = q >> 2, c = q & 3;
        const bool live1 = p ? live1_p1 : live1_p0;

        // ---- issue next step's A loads EARLY (off the critical chain) ----
        float4 n0x, n0y, n1x, n1y;
        const bool havenext = (q + 1 < QMAX);
        if (havenext) {
            const int pn = (q + 1) >> 2, cn = (q + 1) & 3;
            const float4* p0 = aPtr(pn, 0, cn); n0x = p0[0]; n0y = p0[1];
            const float4* p1 = aPtr(pn, 1, cn); n1x = p1[0]; n1y = p1[1];
        }

        // ---- B fragments: prefab, 1KB/wave contiguous, L2-hot ----
        short8 Bh[8], Bl[8];
        const int rbase = c * 512 + quad * 16 + col;
        #pragma unroll
        for (int n = 0; n < 8; ++n) {
            Bh[n] = uh[rbase + n * 64];
            Bl[n] = ul[rbase + n * 64];
        }

        // ---- split current A (registers; data loaded last step) ----
        short8 Ah0, Al0, Ah1, Al1;
        split8r(a0x, a0y, Ah0, Al0);
        split8r(a1x, a1y, Ah1, Al1);

        // ---- MFMA burst: identical per-accumulator order to the verified
        //      kernel: (Ah,Bh),(Ah,Bl),(Al,Bh), chunks in order ----
        #pragma unroll
        for (int n = 0; n < 8; ++n) {
            C[0][n] = __builtin_amdgcn_mfma_f32_16x16x32_bf16(Ah0, Bh[n], C[0][n], 0, 0, 0);
            C[0][n] = __builtin_amdgcn_mfma_f32_16x16x32_bf16(Ah0, Bl[n], C[0][n], 0, 0, 0);
            C[0][n] = __builtin_amdgcn_mfma_f32_16x16x32_bf16(Al0, Bh[n], C[0][n], 0, 0, 0);
            if (live1) {
                C[1][n] = __builtin_amdgcn_mfma_f32_16x16x32_bf16(Ah1, Bh[n], C[1][n], 0, 0, 0);
                C[1][n] = __builtin_amdgcn_mfma_f32_16x16x32_bf16(Ah1, Bl[n], C[1][n], 0, 0, 0);
                C[1][n] = __builtin_amdgcn_mfma_f32_16x16x32_bf16(Al1, Bh[n], C[1][n], 0, 0, 0);
            }
        }

        if (havenext) { a0x = n0x; a0y = n0y; a1x = n1x; a1y = n1y; }

        // ---- end of pass: epilogue (verbatim math), then reset C ----
        if (c == 3) {
            #pragma unroll
            for (int t = 0; t < 2; ++t) {
                if (t == 1 && !live1) continue;   // skip dead tile (wave-uniform)
                float a0 = 0.f, a1 = 0.f, a2 = 0.f, a3 = 0.f;
                #pragma unroll
                for (int n = 0; n < 8; ++n) {
                    float lmc = s_lm[n * 16 + col];
                    float vrc = s_vr[n * 16 + col];
                    a0 = fmaf(vrc, fast_tanh(C[t][n][0] + lmc), a0);
                    a1 = fmaf(vrc, fast_tanh(C[t][n][1] + lmc), a1);
                    a2 = fmaf(vrc, fast_tanh(C[t][n][2] + lmc), a2);
                    a3 = fmaf(vrc, fast_tanh(C[t][n][3] + lmc), a3);
                }
                #pragma unroll
                for (int off = 1; off < 16; off <<= 1) {
                    a0 += __shfl_xor(a0, off, 64);
                    a1 += __shfl_xor(a1, off, 64);
                    a2 += __shfl_xor(a2, off, 64);
                    a3 += __shfl_xor(a3, off, 64);
                }
                if (col == 0) {
                    int rb = row0 + (p * 2 + t) * 16 + quad * 4;
                    s_score[rb + 0] = a0;
                    s_score[rb + 1] = a1;
                    s_score[rb + 2] = a2;
                    s_score[rb + 3] = a3;
                }
            }
            if (q == 3 && QMAX == 8) {
                #pragma unroll
                for (int t = 0; t < 2; ++t)
                    #pragma unroll
                    for (int n = 0; n < 8; ++n)
                        C[t][n] = (f32x4){0.f, 0.f, 0.f, 0.f};
            }
        }
    }

    // ---- zero-fill this batch's output row (AFTER mfma loads: stores don't
    //      block the k-loop's vmcnt waits; drained at the next barrier).
    //      Overlaps with other blocks' MFMA phases; wave 3 starts early. ----
    {
        float4* orow = reinterpret_cast<float4*>(out + (size_t)b * NI);
        const float4 z4 = make_float4(0.f, 0.f, 0.f, 0.f);
        for (int i = tid; i < NI / 4; i += 256) orow[i] = z4;
    }

    __syncthreads();   // s_score visible; fill stores drained (atomics after)

    // ---- softmax over S (verbatim; s_score[s>=200] garbage never used) ----
    const int s = tid;
    float score = s_score[s] + Vrb[0];
    if (s < SS && mask[b * SS + s]) score = -1e9f;

    float v = (s < SS) ? score : -3.0e38f;
    #pragma unroll
    for (int off = 32; off > 0; off >>= 1)
        v = fmaxf(v, __shfl_down(v, off, 64));
    if (lane == 0) s_red[w] = v;
    __syncthreads();
    float m = fmaxf(fmaxf(s_red[0], s_red[1]), fmaxf(s_red[2], s_red[3]));

    float e = (s < SS) ? __expf(score - m) : 0.f;
    float sv = e;
    #pragma unroll
    for (int off = 32; off > 0; off >>= 1)
        sv += __shfl_down(sv, off, 64);
    if (lane == 0) s_red[4 + w] = sv;
    __syncthreads();
    float tot = (s_red[4] + s_red[5]) + (s_red[6] + s_red[7]);

    // ---- scatter-add (row private to block; in-row duplicate ids -> atomics)
    if (s < SS) {
        float att = e / tot;
        int idx = item_seq[b * SS + s];
        atomicAdd(out + (size_t)b * NI + idx, att);
    }
}

// ---------------------------------------------------------------------------
// Fallback: original fused kernel (used only if ws_size is too small).
// ---------------------------------------------------------------------------
__global__ __launch_bounds__(256, 2)
void rrd_mfma_kernel(const float* __restrict__ allm,      // [B,S,H]
                     const float* __restrict__ lastm,     // [B,H]
                     const int* __restrict__ item_seq,    // [B,S]
                     const unsigned char* __restrict__ mask, // [B,S]
                     const float* __restrict__ Ur,        // [H,H]
                     const float* __restrict__ Wr,        // [H,H]
                     const float* __restrict__ Vr,        // [1,H]
                     const float* __restrict__ Vrb,       // [1]
                     float* __restrict__ out) {           // [B,N]
    const int b = blockIdx.x;
    const int tid = threadIdx.x;
    const int lane = tid & 63;
    const int w = tid >> 6;
    const int col = lane & 15;
    const int quad = lane >> 4;

    __shared__ float s_last[HH];
    __shared__ float s_lm[HH];
    __shared__ float s_vr[HH];
    __shared__ float s_score[256];
    __shared__ float s_red[8];

    if (tid < HH) s_last[tid] = lastm[b * HH + tid];
    else          s_vr[tid - HH] = Vr[tid - HH];
    __syncthreads();

    if (tid < HH) {
        const float4* wrow = reinterpret_cast<const float4*>(Wr + tid * HH);
        const float4* lrow = reinterpret_cast<const float4*>(s_last);
        float4 acc = make_float4(0.f, 0.f, 0.f, 0.f);
        #pragma unroll
        for (int i = 0; i < HH / 4; ++i) {
            float4 wv = wrow[i];
            float4 lv = lrow[i];
            acc.x = fmaf(lv.x, wv.x, acc.x);
            acc.y = fmaf(lv.y, wv.y, acc.y);
            acc.z = fmaf(lv.z, wv.z, acc.z);
            acc.w = fmaf(lv.w, wv.w, acc.w);
        }
        s_lm[tid] = (acc.x + acc.y) + (acc.z + acc.w);
    }
    __syncthreads();

    const int row0 = w * 64;
    #pragma unroll 1
    for (int p = 0; p < 2; ++p) {
        f32x4 C[2][8] = {};
        #pragma unroll 1
        for (int c = 0; c < 4; ++c) {
            short8 Bh[8], Bl[8];
            #pragma unroll
            for (int n = 0; n < 8; ++n) {
                const float* bp = Ur + (size_t)(n * 16 + col) * HH + c * 32 + quad * 8;
                split8(bp, Bh[n], Bl[n]);
            }
            #pragma unroll
            for (int t = 0; t < 2; ++t) {
                int row = row0 + (p * 2 + t) * 16 + col;
                if (row > SS - 1) row = SS - 1;
                const float* ap = allm + ((size_t)b * SS + row) * HH + c * 32 + quad * 8;
                short8 Ah, Al;
                split8(ap, Ah, Al);
                #pragma unroll
                for (int n = 0; n < 8; ++n) {
                    C[t][n] = __builtin_amdgcn_mfma_f32_16x16x32_bf16(Ah, Bh[n], C[t][n], 0, 0, 0);
                    C[t][n] = __builtin_amdgcn_mfma_f32_16x16x32_bf16(Ah, Bl[n], C[t][n], 0, 0, 0);
                    C[t][n] = __builtin_amdgcn_mfma_f32_16x16x32_bf16(Al, Bh[n], C[t][n], 0, 0, 0);
                }
            }
        }
        #pragma unroll
        for (int t = 0; t < 2; ++t) {
            float a0 = 0.f, a1 = 0.f, a2 = 0.f, a3 = 0.f;
            #pragma unroll
            for (int n = 0; n < 8; ++n) {
                float lmc = s_lm[n * 16 + col];
                float vrc = s_vr[n * 16 + col];
                a0 = fmaf(vrc, fast_tanh(C[t][n][0] + lmc), a0);
                a1 = fmaf(vrc, fast_tanh(C[t][n][1] + lmc), a1);
                a2 = fmaf(vrc, fast_tanh(C[t][n][2] + lmc), a2);
                a3 = fmaf(vrc, fast_tanh(C[t][n][3] + lmc), a3);
            }
            #pragma unroll
            for (int off = 1; off < 16; off <<= 1) {
                a0 += __shfl_xor(a0, off, 64);
                a1 += __shfl_xor(a1, off, 64);
                a2 += __shfl_xor(a2, off, 64);
                a3 += __shfl_xor(a3, off, 64);
            }
            if (col == 0) {
                int rb = row0 + (p * 2 + t) * 16 + quad * 4;
                s_score[rb + 0] = a0;
                s_score[rb + 1] = a1;
                s_score[rb + 2] = a2;
                s_score[rb + 3] = a3;
            }
        }
    }

    {
        float4* orow = reinterpret_cast<float4*>(out + (size_t)b * NI);
        const float4 z4 = make_float4(0.f, 0.f, 0.f, 0.f);
        for (int i = tid; i < NI / 4; i += 256) orow[i] = z4;
    }

    __syncthreads();

    const int s = tid;
    float score = s_score[s] + Vrb[0];
    if (s < SS && mask[b * SS + s]) score = -1e9f;

    float v = (s < SS) ? score : -3.0e38f;
    #pragma unroll
    for (int off = 32; off > 0; off >>= 1)
        v = fmaxf(v, __shfl_down(v, off, 64));
    if (lane == 0) s_red[w] = v;
    __syncthreads();
    float m = fmaxf(fmaxf(s_red[0], s_red[1]), fmaxf(s_red[2], s_red[3]));

    float e = (s < SS) ? __expf(score - m) : 0.f;
    float sv = e;
    #pragma unroll
    for (int off = 32; off > 0; off >>= 1)
        sv += __shfl_down(sv, off, 64);
    if (lane == 0) s_red[4 + w] = sv;
    __syncthreads();
    float tot = (s_red[4] + s_red[5]) + (s_red[6] + s_red[7]);

    if (s < SS) {
        float att = e / tot;
        int idx = item_seq[b * SS + s];
        atomicAdd(out + (size_t)b * NI + idx, att);
    }
}

extern "C" void kernel_launch(void* const* d_in, const int* in_sizes, int n_in,
                              void* d_out, int out_size, void* d_ws, size_t ws_size,
                              hipStream_t stream) {
    const float* allm   = (const float*)d_in[0];
    const float* lastm  = (const float*)d_in[1];
    const int*   iseq   = (const int*)d_in[2];
    const unsigned char* mask = (const unsigned char*)d_in[3];
    const float* Ur     = (const float*)d_in[4];
    const float* Wr     = (const float*)d_in[5];
    const float* Vr     = (const float*)d_in[6];
    const float* Vrb    = (const float*)d_in[7];
    float* out          = (float*)d_out;

    const size_t lm_bytes = (size_t)BB * HH * sizeof(float);    // 512 KB
    const size_t ur_bytes = (size_t)HH * HH * sizeof(short);    // 32 KB each
    const size_t need = lm_bytes + 2 * ur_bytes;                // 576 KB

    if (d_ws != nullptr && ws_size >= need) {
        float* lm_ws = (float*)d_ws;
        short* ur_hi = (short*)((char*)d_ws + lm_bytes);
        short* ur_lo = (short*)((char*)d_ws + lm_bytes + ur_bytes);
        rrd_prep_kernel<<<dim3(520), dim3(256), 0, stream>>>(
            lastm, Wr, Ur, lm_ws, ur_hi, ur_lo);
        rrd_mfma_kernel_p<<<dim3(BB), dim3(256), 0, stream>>>(
            allm, iseq, mask, ur_hi, ur_lo, lm_ws, Vr, Vrb, out);
    } else {
        rrd_mfma_kernel<<<dim3(BB), dim3(256), 0, stream>>>(
            allm, lastm, iseq, mask, Ur, Wr, Vr, Vrb, out);
    }
}